// Round 5
// baseline (136.994 us; speedup 1.0000x reference)
//
#include <hip/hip_runtime.h>
#include <hip/hip_bf16.h>

#define NB 4
#define NN 2048
#define ND 512
#define NE 16
#define NH 1024
#define CAP 256
#define NTOK (NB*NN)

typedef __attribute__((ext_vector_type(8))) short bf16x8;
typedef __attribute__((ext_vector_type(4))) float f32x4;
typedef __attribute__((ext_vector_type(8))) unsigned short u16x8;

__device__ __forceinline__ void gload16(const void* gsrc, void* lds) {
    __builtin_amdgcn_global_load_lds((const __attribute__((address_space(1))) void*)gsrc,
                                     (__attribute__((address_space(3))) void*)lds, 16, 0, 0);
}
__device__ __forceinline__ unsigned short f2bf(float f) {
    union { __hip_bfloat16 b; unsigned short u; } v; v.b = __float2bfloat16(f); return v.u;
}

// ---------------- fused prep (serial blocks first, then streaming) ----------------
// [0,1024)      u[e][h] = We2[e][h][:] . (W3@W4)      (float4, 4-row ILP)
// [1024,1056)   WcT[e][d] = (W1@Wg)^T                 (byte-identical math to R2/R3)
// [1056,1184)   W1^T  f32[512][512] -> bf16[512][512] (32x64 tiles)
// [1184,5280)   We1^T f32[e][512][1024] -> bf16[e][1024][512]
// [5280,7328)   X -> bf16 (8 elem/thread)
__global__ __launch_bounds__(256) void prep_kernel(const float* __restrict__ X,
                                                   const float* __restrict__ W1,
                                                   const float* __restrict__ Wg,
                                                   const float* __restrict__ We1,
                                                   const float* __restrict__ We2,
                                                   const float* __restrict__ W3,
                                                   const float* __restrict__ W4,
                                                   unsigned short* __restrict__ Xbf,
                                                   unsigned short* __restrict__ W1T,
                                                   unsigned short* __restrict__ We1T,
                                                   float* __restrict__ WcT,
                                                   float* __restrict__ u,
                                                   float* __restrict__ zbuf) {
    const int tid = threadIdx.x;
    int bid = blockIdx.x;
    if (bid < 1024) {                                   // ---- u (reads We2 32MB, float4)
        __shared__ float vvs[ND];
        {
            int d = tid * 2;
            float s0 = 0.f, s1 = 0.f;
            #pragma unroll
            for (int j = 0; j < 4; ++j) {
                s0 += W3[d * 4 + j] * W4[j];
                s1 += W3[(d + 1) * 4 + j] * W4[j];
            }
            vvs[d] = s0; vvs[d + 1] = s1;
        }
        if (bid == 0) zbuf[tid] = 0.f;
        __syncthreads();
        const int w = tid >> 6, l = tid & 63;
        const float4* vv4 = (const float4*)vvs;
        const float4 v0 = vv4[l], v1 = vv4[l + 64];
        float sums[4];
        #pragma unroll
        for (int i = 0; i < 4; ++i) {
            int gr = bid * 16 + w * 4 + i;
            const float4* row = (const float4*)(We2 + (size_t)gr * ND);
            float4 a0 = row[l], a1 = row[l + 64];
            sums[i] = a0.x * v0.x + a0.y * v0.y + a0.z * v0.z + a0.w * v0.w
                    + a1.x * v1.x + a1.y * v1.y + a1.z * v1.z + a1.w * v1.w;
        }
        #pragma unroll
        for (int off = 32; off >= 1; off >>= 1)
            #pragma unroll
            for (int i = 0; i < 4; ++i) sums[i] += __shfl_xor(sums[i], off);
        if (l == 0) {
            int gr0 = bid * 16 + w * 4;
            u[gr0 + 0] = sums[0]; u[gr0 + 1] = sums[1];
            u[gr0 + 2] = sums[2]; u[gr0 + 3] = sums[3];
        }
        return;
    }
    bid -= 1024;
    if (bid < 32) {                                     // ---- WcT (keep summation order!)
        int d = bid * 16 + (tid >> 4);
        int e = tid & 15;
        float s = 0.f;
        for (int j = 0; j < ND; ++j) s = fmaf(W1[d * ND + j], Wg[j * NE + e], s);
        WcT[e * ND + d] = s;
        return;
    }
    bid -= 32;
    if (bid < 128 + 4096) {                             // ---- transposes, 32r x 64c tiles
        const float* src; unsigned short* dst; int C; size_t zoff; int bx, by;
        const int R = ND;
        if (bid < 128) { src = W1; dst = W1T; C = ND; zoff = 0; by = bid >> 3; bx = bid & 7; }
        else {
            int tb = bid - 128;
            int z = tb >> 8, rem = tb & 255;
            src = We1; dst = We1T; C = NH;
            zoff = (size_t)z * ND * NH; by = rem >> 4; bx = rem & 15;
        }
        __shared__ float t[32][68];
        const int r0 = by * 32, c0 = bx * 64;
        #pragma unroll
        for (int i = 0; i < 2; ++i) {
            int idx = tid + 256 * i;
            int row = idx >> 4, col4 = (idx & 15) * 4;
            *(float4*)(&t[row][col4]) = *(const float4*)(src + zoff + (size_t)(r0 + row) * C + c0 + col4);
        }
        __syncthreads();
        {   // store: 64 cols x 4 row-segments = exactly 256 items (one pass!)
            int c = tid >> 2, rseg = (tid & 3) * 8;
            u16x8 o;
            #pragma unroll
            for (int j = 0; j < 8; ++j) o[j] = f2bf(t[rseg + j][c]);
            *(u16x8*)(dst + zoff + (size_t)(c0 + c) * R + r0 + rseg) = o;
        }
        return;
    }
    bid -= 4224;
    {                                                   // ---- X -> bf16, 8/thread
        size_t i0 = ((size_t)bid * 256 + tid) * 8;
        float4 a = *(const float4*)(X + i0);
        float4 b = *(const float4*)(X + i0 + 4);
        u16x8 o;
        o[0] = f2bf(a.x); o[1] = f2bf(a.y); o[2] = f2bf(a.z); o[3] = f2bf(a.w);
        o[4] = f2bf(b.x); o[5] = f2bf(b.y); o[6] = f2bf(b.z); o[7] = f2bf(b.w);
        *(u16x8*)(Xbf + i0) = o;
    }
}

// ---------------- linear1 MFMA: hbf = bf16( Xbf @ W1 + b1 ) ----------------
__global__ __launch_bounds__(512) void linear1_mfma_kernel(const unsigned short* __restrict__ Xbf,
                                                           const unsigned short* __restrict__ W1T,
                                                           const float* __restrict__ b1,
                                                           unsigned short* __restrict__ hbf) {
    __shared__ char Ash[2][16384];
    __shared__ char Bsh[2][16384];
    const int tid = threadIdx.x;
    const int w = tid >> 6, l = tid & 63;
    const int wm = w >> 1, wn = w & 1;      // 4 x 2 wave grid, wave tile 32x64
    const int lr = l & 15, lk = l >> 4;
    const int m0 = blockIdx.y * 128, n0 = blockIdx.x * 128;

    auto stage = [&](int Ks, int buf) {
        #pragma unroll
        for (int i = 0; i < 2; ++i) {
            int o = i * 8192 + tid * 16;
            int r = o >> 7, bb = o & 127;
            int sb = bb ^ ((r & 7) << 4);
            gload16((const char*)Xbf + ((size_t)(m0 + r) * ND + Ks * 64) * 2 + sb,
                    Ash[buf] + i * 8192 + w * 1024);
            gload16((const char*)W1T + ((size_t)(n0 + r) * ND + Ks * 64) * 2 + sb,
                    Bsh[buf] + i * 8192 + w * 1024);
        }
    };

    f32x4 acc[2][4] = {};
    stage(0, 0);
    __syncthreads();
    for (int Ks = 0; Ks < 8; ++Ks) {
        int buf = Ks & 1;
        if (Ks < 7) stage(Ks + 1, buf ^ 1);
        #pragma unroll
        for (int k32 = 0; k32 < 2; ++k32) {
            int kb = (k32 * 32 + 8 * lk) * 2;
            bf16x8 a[2], bfr[4];
            #pragma unroll
            for (int mi = 0; mi < 2; ++mi) {
                int row = wm * 32 + mi * 16 + lr;
                a[mi] = *(const bf16x8*)(Ash[buf] + row * 128 + (kb ^ ((row & 7) << 4)));
            }
            #pragma unroll
            for (int ni = 0; ni < 4; ++ni) {
                int row = wn * 64 + ni * 16 + lr;
                bfr[ni] = *(const bf16x8*)(Bsh[buf] + row * 128 + (kb ^ ((row & 7) << 4)));
            }
            #pragma unroll
            for (int mi = 0; mi < 2; ++mi)
                #pragma unroll
                for (int ni = 0; ni < 4; ++ni)
                    acc[mi][ni] = __builtin_amdgcn_mfma_f32_16x16x32_bf16(a[mi], bfr[ni], acc[mi][ni], 0, 0, 0);
        }
        __syncthreads();
    }
    #pragma unroll
    for (int mi = 0; mi < 2; ++mi)
        #pragma unroll
        for (int ni = 0; ni < 4; ++ni) {
            int col = n0 + wn * 64 + ni * 16 + lr;
            float bb1 = b1[col];
            #pragma unroll
            for (int r = 0; r < 4; ++r) {
                int m = m0 + wm * 32 + mi * 16 + lk * 4 + r;
                hbf[(size_t)m * ND + col] = f2bf(acc[mi][ni][r] + bb1);
            }
        }
}

// ---------------- gating from X and WcT (f32, float4 loads) ----------------
__global__ __launch_bounds__(256) void gating_kernel(const float* __restrict__ X,
                                                     const float* __restrict__ WcT,
                                                     const float* __restrict__ probs,
                                                     int* __restrict__ idx1a, int* __restrict__ idx2a,
                                                     float* __restrict__ g1a, float* __restrict__ g2a,
                                                     int* __restrict__ pos1a, int* __restrict__ pos2a) {
    __shared__ float wc[NE * ND];           // 32KB
    const int tid = threadIdx.x;
    #pragma unroll
    for (int i = 0; i < 32; ++i) wc[tid + 256 * i] = WcT[tid + 256 * i];
    __syncthreads();
    const int w = tid >> 6, l = tid & 63;
    const float4* wc4 = (const float4*)wc;
    for (int j = 0; j < 8; ++j) {
        int tok = blockIdx.x * 32 + j * 4 + w;
        const float4* xrow = (const float4*)(X + (size_t)tok * ND);
        float4 x0 = xrow[l], x1 = xrow[l + 64];
        float acc[NE];
        #pragma unroll
        for (int e = 0; e < NE; ++e) {
            float4 w0 = wc4[e * 128 + l], w1 = wc4[e * 128 + l + 64];
            acc[e] = x0.x * w0.x + x0.y * w0.y + x0.z * w0.z + x0.w * w0.w
                   + x1.x * w1.x + x1.y * w1.y + x1.z * w1.z + x1.w * w1.w;
        }
        #pragma unroll
        for (int off = 32; off >= 1; off >>= 1)
            #pragma unroll
            for (int e = 0; e < NE; ++e) acc[e] += __shfl_xor(acc[e], off);

        if (l == 0) {
            float m = acc[0];
            #pragma unroll
            for (int e = 1; e < NE; ++e) m = fmaxf(m, acc[e]);
            float raw[NE]; float s = 0.f;
            #pragma unroll
            for (int e = 0; e < NE; ++e) { raw[e] = expf(acc[e] - m); s += raw[e]; }
            #pragma unroll
            for (int e = 0; e < NE; ++e) raw[e] = raw[e] / s;
            int i1 = 0; float g1 = raw[0];
            #pragma unroll
            for (int e = 1; e < NE; ++e) if (raw[e] > g1) { g1 = raw[e]; i1 = e; }
            int i2 = -1; float g2 = -1.f;
            #pragma unroll
            for (int e = 0; e < NE; ++e) if (e != i1 && raw[e] > g2) { g2 = raw[e]; i2 = e; }
            float denom = g1 + g2 + 1e-9f;
            float g1n = g1 / denom, g2n = g2 / denom;
            bool flag = probs[tok] < (g2n / 0.2f);
            idx1a[tok] = i1;
            idx2a[tok] = flag ? i2 : -1;
            g1a[tok] = g1n;
            g2a[tok] = g2n;
            pos1a[tok] = -1;
            pos2a[tok] = -1;
        }
    }
}

// ---------------- scan: one wave per (b,e), ballot prefix cumsum ----------------
__global__ __launch_bounds__(64) void scan_kernel(const int* __restrict__ idx1a,
                                                  const int* __restrict__ idx2a,
                                                  int* __restrict__ pos1a, int* __restrict__ pos2a,
                                                  int* __restrict__ slot_token) {
    const int bb = blockIdx.x;              // 64
    const int b = bb >> 4, e = bb & 15;
    const int l = threadIdx.x;
    int* slot = slot_token + (e * NB + b) * CAP;
    const unsigned long long below = (l == 0) ? 0ull : ((1ull << l) - 1ull);
    int c = 0;
    for (int base = 0; base < NN; base += 64) {
        int n = base + l;
        bool p = (idx1a[b * NN + n] == e);
        unsigned long long m = __ballot(p);
        int pre = __popcll(m & below);
        if (p) {
            int pos = c + pre;
            if (pos < CAP) { slot[pos] = n; pos1a[b * NN + n] = pos; }
        }
        c += __popcll(m);
    }
    int c2 = (c < CAP) ? c : CAP;
    for (int base = 0; base < NN; base += 64) {
        int n = base + l;
        bool p = (idx2a[b * NN + n] == e);
        unsigned long long m = __ballot(p);
        int pre = __popcll(m & below);
        if (p) {
            int pos = c2 + pre;
            if (pos < CAP) { slot[pos] = n; pos2a[b * NN + n] = pos; }
        }
        c2 += __popcll(m);
    }
    int nfill = (c2 < CAP) ? c2 : CAP;
    for (int i = nfill + l; i < CAP; i += 64) slot[i] = -1;
}

// ---------------- expert MFMA with expert->XCD swizzle ----------------
__global__ __launch_bounds__(512) void expert_mfma_kernel(const unsigned short* __restrict__ hbf,
                                                          const unsigned short* __restrict__ We1T,
                                                          const float* __restrict__ u,
                                                          const int* __restrict__ slot_token,
                                                          const float* __restrict__ zbuf,
                                                          float* __restrict__ s_slot) {
    __shared__ char Ash[65536];             // 64 slots x 512 k bf16, swizzled rows of 1024B
    __shared__ char Bsh[2][32768];          // 256 h x 64 k bf16, swizzled rows of 128B
    __shared__ float u_lds[NH];
    __shared__ float sbuf[8][32];
    __shared__ int toks[64];
    const int tid = threadIdx.x;
    const int w = tid >> 6, l = tid & 63;
    const int wm = w >> 2, wn = w & 3;      // 2 x 4 wave grid, wave tile 32x64
    const int lr = l & 15, lk = l >> 4;
    // XCD swizzle: all 16 blocks of an expert share an XCD (bid % 8 == e % 8)
    const int bid = blockIdx.x;
    const int e = (bid & 7) | ((bid >> 7) << 3);
    const int chunk = (bid >> 3) & 15;
    const int b = chunk >> 2, c0 = (chunk & 3) * 64;

    if (tid < 64) toks[tid] = slot_token[(e * NB + b) * CAP + c0 + tid];
    u_lds[tid] = u[e * NH + tid];
    u_lds[tid + 512] = u[e * NH + tid + 512];
    __syncthreads();
    // stage A: gather 64 token rows (full K) into LDS, swizzled source (rule #21)
    #pragma unroll
    for (int i = 0; i < 8; ++i) {
        int r = i * 8 + w;                  // wave-uniform row
        int t = toks[r];
        int sb = (l * 16) ^ ((r & 7) << 4);
        const char* src = (t >= 0) ? ((const char*)hbf + ((size_t)(b * NN + t) * ND) * 2 + sb)
                                   : ((const char*)zbuf + sb);
        gload16(src, Ash + i * 8192 + w * 1024);
    }
    auto stageB = [&](int s, int buf) {
        int Hc = s >> 3, Ks = s & 7;
        #pragma unroll
        for (int i = 0; i < 4; ++i) {
            int o = i * 8192 + tid * 16;
            int r = o >> 7, bb = o & 127;
            int sb = bb ^ ((r & 7) << 4);
            gload16((const char*)We1T + ((size_t)(e * NH + Hc * 256 + r) * ND + Ks * 64) * 2 + sb,
                    Bsh[buf] + i * 8192 + w * 1024);
        }
    };
    f32x4 acc[2][4] = {};
    float srow[2][4] = {};
    stageB(0, 0);
    __syncthreads();
    for (int s = 0; s < 32; ++s) {          // 4 H-chunks x 8 K-stages
        int buf = s & 1;
        if (s < 31) stageB(s + 1, buf ^ 1);
        #pragma unroll
        for (int k32 = 0; k32 < 2; ++k32) {
            int kbA = ((s & 7) * 64 + k32 * 32 + 8 * lk) * 2;
            int kbB = (k32 * 32 + 8 * lk) * 2;
            bf16x8 a[2], bfr[4];
            #pragma unroll
            for (int mi = 0; mi < 2; ++mi) {
                int row = wm * 32 + mi * 16 + lr;
                a[mi] = *(const bf16x8*)(Ash + row * 1024 + (kbA ^ ((row & 7) << 4)));
            }
            #pragma unroll
            for (int ni = 0; ni < 4; ++ni) {
                int row = wn * 64 + ni * 16 + lr;
                bfr[ni] = *(const bf16x8*)(Bsh[buf] + row * 128 + (kbB ^ ((row & 7) << 4)));
            }
            #pragma unroll
            for (int mi = 0; mi < 2; ++mi)
                #pragma unroll
                for (int ni = 0; ni < 4; ++ni)
                    acc[mi][ni] = __builtin_amdgcn_mfma_f32_16x16x32_bf16(a[mi], bfr[ni], acc[mi][ni], 0, 0, 0);
        }
        if ((s & 7) == 7) {                 // H-chunk done: fuse lrelu . u, reset acc
            int Hc = s >> 3;
            #pragma unroll
            for (int mi = 0; mi < 2; ++mi)
                #pragma unroll
                for (int ni = 0; ni < 4; ++ni) {
                    float uu = u_lds[Hc * 256 + wn * 64 + ni * 16 + lr];
                    #pragma unroll
                    for (int r = 0; r < 4; ++r) {
                        float x = acc[mi][ni][r];
                        x = (x > 0.f) ? x : 0.01f * x;
                        srow[mi][r] = fmaf(x, uu, srow[mi][r]);
                        acc[mi][ni][r] = 0.f;
                    }
                }
        }
        __syncthreads();
    }
    // reduce over the 16 col-lanes, then across the 4 N-waves via LDS
    #pragma unroll
    for (int off = 1; off < 16; off <<= 1)
        #pragma unroll
        for (int mi = 0; mi < 2; ++mi)
            #pragma unroll
            for (int r = 0; r < 4; ++r)
                srow[mi][r] += __shfl_xor(srow[mi][r], off);
    if (lr == 0) {
        #pragma unroll
        for (int mi = 0; mi < 2; ++mi)
            #pragma unroll
            for (int r = 0; r < 4; ++r)
                sbuf[w][mi * 16 + lk * 4 + r] = srow[mi][r];
    }
    __syncthreads();
    if (tid < 64) {
        int q = tid >> 5, rl = tid & 31;
        float s = sbuf[q * 4 + 0][rl] + sbuf[q * 4 + 1][rl] + sbuf[q * 4 + 2][rl] + sbuf[q * 4 + 3][rl];
        s_slot[(e * NB + b) * CAP + c0 + tid] = s;
    }
}

// ---------------- final combine + collapsed output projection ----------------
__global__ __launch_bounds__(256) void final_kernel(const int* __restrict__ idx1a, const int* __restrict__ idx2a,
                                                    const int* __restrict__ pos1a, const int* __restrict__ pos2a,
                                                    const float* __restrict__ g1a, const float* __restrict__ g2a,
                                                    const float* __restrict__ s_slot,
                                                    const float* __restrict__ b3, const float* __restrict__ W4,
                                                    const float* __restrict__ b4,
                                                    float* __restrict__ out) {
    int tok = blockIdx.x * 256 + threadIdx.x;
    int b = tok >> 11;
    float c0v = 0.f;
    #pragma unroll
    for (int j = 0; j < 4; ++j) c0v += b3[j] * W4[j];
    float s = c0v + b4[0];
    int p1 = pos1a[tok];
    if (p1 >= 0) s += g1a[tok] * s_slot[(idx1a[tok] * NB + b) * CAP + p1];
    int p2 = pos2a[tok];
    if (p2 >= 0) s += g2a[tok] * s_slot[(idx2a[tok] * NB + b) * CAP + p2];
    out[tok] = s;
}

extern "C" void kernel_launch(void* const* d_in, const int* in_sizes, int n_in,
                              void* d_out, int out_size, void* d_ws, size_t ws_size,
                              hipStream_t stream) {
    const float* X    = (const float*)d_in[0];
    const float* probs= (const float*)d_in[1];
    const float* W1   = (const float*)d_in[2];
    const float* b1   = (const float*)d_in[3];
    const float* Wg   = (const float*)d_in[4];
    const float* We1  = (const float*)d_in[5];
    const float* We2  = (const float*)d_in[6];
    const float* W3   = (const float*)d_in[7];
    const float* b3   = (const float*)d_in[8];
    const float* W4   = (const float*)d_in[9];
    const float* b4   = (const float*)d_in[10];
    float* out = (float*)d_out;

    char* ws = (char*)d_ws;
    size_t off = 0;
    auto alloc = [&](size_t bytes) { void* p = ws + off; off += (bytes + 255) & ~(size_t)255; return p; };
    unsigned short* Xbf  = (unsigned short*)alloc((size_t)NTOK * ND * 2);     // 8 MB
    unsigned short* hbf  = (unsigned short*)alloc((size_t)NTOK * ND * 2);     // 8 MB
    unsigned short* W1T  = (unsigned short*)alloc((size_t)ND * ND * 2);       // 512 KB
    unsigned short* We1T = (unsigned short*)alloc((size_t)NE * NH * ND * 2);  // 16 MB
    float* WcT     = (float*)alloc(NE * ND * 4);
    float* u       = (float*)alloc(NE * NH * 4);
    float* zbuf    = (float*)alloc(1024);
    int*   idx1a   = (int*)alloc(NTOK * 4);
    int*   idx2a   = (int*)alloc(NTOK * 4);
    int*   pos1a   = (int*)alloc(NTOK * 4);
    int*   pos2a   = (int*)alloc(NTOK * 4);
    float* g1a     = (float*)alloc(NTOK * 4);
    float* g2a     = (float*)alloc(NTOK * 4);
    int*   slot_tok= (int*)alloc(NE * NB * CAP * 4);
    float* s_slot  = (float*)alloc(NE * NB * CAP * 4);
    (void)ws_size; (void)in_sizes; (void)n_in; (void)out_size;

    prep_kernel<<<7328, 256, 0, stream>>>(X, W1, Wg, We1, We2, W3, W4,
                                          Xbf, W1T, We1T, WcT, u, zbuf);
    linear1_mfma_kernel<<<dim3(ND / 128, NTOK / 128), 512, 0, stream>>>(Xbf, W1T, b1, hbf);
    gating_kernel<<<NTOK / 32, 256, 0, stream>>>(X, WcT, probs, idx1a, idx2a, g1a, g2a, pos1a, pos2a);
    scan_kernel<<<NB * NE, 64, 0, stream>>>(idx1a, idx2a, pos1a, pos2a, slot_tok);
    expert_mfma_kernel<<<256, 512, 0, stream>>>(hbf, We1T, u, slot_tok, zbuf, s_slot);
    final_kernel<<<NTOK / 256, 256, 0, stream>>>(idx1a, idx2a, pos1a, pos2a, g1a, g2a, s_slot, b3, W4, b4, out);
}

// Round 6
// 136.270 us; speedup vs baseline: 1.0053x; 1.0053x over previous
//
#include <hip/hip_runtime.h>
#include <hip/hip_bf16.h>

#define NB 4
#define NN 2048
#define ND 512
#define NE 16
#define NH 1024
#define CAP 256
#define NTOK (NB*NN)

typedef __attribute__((ext_vector_type(8))) short bf16x8;
typedef __attribute__((ext_vector_type(4))) float f32x4;
typedef __attribute__((ext_vector_type(8))) unsigned short u16x8;

__device__ __forceinline__ void gload16(const void* gsrc, void* lds) {
    __builtin_amdgcn_global_load_lds((const __attribute__((address_space(1))) void*)gsrc,
                                     (__attribute__((address_space(3))) void*)lds, 16, 0, 0);
}
__device__ __forceinline__ unsigned short f2bf(float f) {
    union { __hip_bfloat16 b; unsigned short u; } v; v.b = __float2bfloat16(f); return v.u;
}

// ---------------- fused prep (serial blocks first, then streaming) ----------------
// [0,1024)      u[e][h] = We2[e][h][:] . (W3@W4)
// [1024,1056)   WcT[e][d] = (W1@Wg)^T
// [1056,1088)   W1  -> W1B  blocked bf16 [Ks=8][n=512][dd=64]   (LDS-free transpose)
// [1088,2112)   We1 -> We1B blocked bf16 [e][Ks=8][h=1024][dd=64]
// [2112,3136)   X -> bf16 natural [m][k] (16 elem/thread)
__global__ __launch_bounds__(256) void prep_kernel(const float* __restrict__ X,
                                                   const float* __restrict__ W1,
                                                   const float* __restrict__ Wg,
                                                   const float* __restrict__ We1,
                                                   const float* __restrict__ We2,
                                                   const float* __restrict__ W3,
                                                   const float* __restrict__ W4,
                                                   unsigned short* __restrict__ Xbf,
                                                   unsigned short* __restrict__ W1B,
                                                   unsigned short* __restrict__ We1B,
                                                   float* __restrict__ WcT,
                                                   float* __restrict__ u,
                                                   float* __restrict__ zbuf) {
    const int tid = threadIdx.x;
    int bid = blockIdx.x;
    if (bid < 1024) {                                   // ---- u (reads We2 32MB, float4)
        __shared__ float vvs[ND];
        {
            int d = tid * 2;
            float s0 = 0.f, s1 = 0.f;
            #pragma unroll
            for (int j = 0; j < 4; ++j) {
                s0 += W3[d * 4 + j] * W4[j];
                s1 += W3[(d + 1) * 4 + j] * W4[j];
            }
            vvs[d] = s0; vvs[d + 1] = s1;
        }
        if (bid == 0) zbuf[tid] = 0.f;
        __syncthreads();
        const int w = tid >> 6, l = tid & 63;
        const float4* vv4 = (const float4*)vvs;
        const float4 v0 = vv4[l], v1 = vv4[l + 64];
        float sums[4];
        #pragma unroll
        for (int i = 0; i < 4; ++i) {
            int gr = bid * 16 + w * 4 + i;
            const float4* row = (const float4*)(We2 + (size_t)gr * ND);
            float4 a0 = row[l], a1 = row[l + 64];
            sums[i] = a0.x * v0.x + a0.y * v0.y + a0.z * v0.z + a0.w * v0.w
                    + a1.x * v1.x + a1.y * v1.y + a1.z * v1.z + a1.w * v1.w;
        }
        #pragma unroll
        for (int off = 32; off >= 1; off >>= 1)
            #pragma unroll
            for (int i = 0; i < 4; ++i) sums[i] += __shfl_xor(sums[i], off);
        if (l == 0) {
            int gr0 = bid * 16 + w * 4;
            u[gr0 + 0] = sums[0]; u[gr0 + 1] = sums[1];
            u[gr0 + 2] = sums[2]; u[gr0 + 3] = sums[3];
        }
        return;
    }
    bid -= 1024;
    if (bid < 32) {                                     // ---- WcT (keep summation order!)
        int d = bid * 16 + (tid >> 4);
        int e = tid & 15;
        float s = 0.f;
        for (int j = 0; j < ND; ++j) s = fmaf(W1[d * ND + j], Wg[j * NE + e], s);
        WcT[e * ND + d] = s;
        return;
    }
    bid -= 32;
    if (bid < 32 + 1024) {                              // ---- blocked transposes, LDS-free
        const float* src; unsigned short* dst; int C; size_t so, dof;
        int d0, h0;
        if (bid < 32) {                                 // W1 [d][n] -> W1B [dblk][n][64]
            int dblk = bid >> 2, nblk = bid & 3;
            src = W1; C = ND; so = 0;
            d0 = dblk * 64; h0 = nblk * 128;
            dst = W1B; dof = (size_t)(dblk * 512 + h0) * 64;
        } else {                                        // We1 [e][d][h] -> We1B [e][dblk][h][64]
            int tb = bid - 32;
            int e = tb >> 6, rem = tb & 63;
            int dblk = rem >> 3, hblk = rem & 7;
            src = We1; C = NH; so = (size_t)e * ND * NH;
            d0 = dblk * 64; h0 = hblk * 128;
            dst = We1B; dof = (size_t)((e * 8 + dblk) * NH + h0) * 64;
        }
        const int hh = tid & 127, s = tid >> 7;         // 128 rows x 2 d-halves
        float v[32];
        #pragma unroll
        for (int j = 0; j < 32; ++j)
            v[j] = src[so + (size_t)(d0 + s * 32 + j) * C + h0 + hh];
        #pragma unroll
        for (int q = 0; q < 4; ++q) {
            u16x8 o;
            #pragma unroll
            for (int j = 0; j < 8; ++j) o[j] = f2bf(v[q * 8 + j]);
            *(u16x8*)(dst + dof + (size_t)hh * 64 + s * 32 + q * 8) = o;
        }
        return;
    }
    bid -= 1056;
    {                                                   // ---- X -> bf16, 16/thread
        size_t i0 = ((size_t)bid * 256 + tid) * 16;
        float4 a = *(const float4*)(X + i0);
        float4 b = *(const float4*)(X + i0 + 4);
        float4 c = *(const float4*)(X + i0 + 8);
        float4 d = *(const float4*)(X + i0 + 12);
        u16x8 o0, o1;
        o0[0] = f2bf(a.x); o0[1] = f2bf(a.y); o0[2] = f2bf(a.z); o0[3] = f2bf(a.w);
        o0[4] = f2bf(b.x); o0[5] = f2bf(b.y); o0[6] = f2bf(b.z); o0[7] = f2bf(b.w);
        o1[0] = f2bf(c.x); o1[1] = f2bf(c.y); o1[2] = f2bf(c.z); o1[3] = f2bf(c.w);
        o1[4] = f2bf(d.x); o1[5] = f2bf(d.y); o1[6] = f2bf(d.z); o1[7] = f2bf(d.w);
        *(u16x8*)(Xbf + i0) = o0;
        *(u16x8*)(Xbf + i0 + 8) = o1;
    }
}

// ---------------- linear1 MFMA: hbf = bf16( Xbf @ W1 + b1 ) ----------------
__global__ __launch_bounds__(512) void linear1_mfma_kernel(const unsigned short* __restrict__ Xbf,
                                                           const unsigned short* __restrict__ W1B,
                                                           const float* __restrict__ b1,
                                                           unsigned short* __restrict__ hbf) {
    __shared__ char Ash[2][16384];
    __shared__ char Bsh[2][16384];
    const int tid = threadIdx.x;
    const int w = tid >> 6, l = tid & 63;
    const int wm = w >> 1, wn = w & 1;      // 4 x 2 wave grid, wave tile 32x64
    const int lr = l & 15, lk = l >> 4;
    const int m0 = blockIdx.y * 128, n0 = blockIdx.x * 128;

    auto stage = [&](int Ks, int buf) {
        #pragma unroll
        for (int i = 0; i < 2; ++i) {
            int o = i * 8192 + tid * 16;
            int r = o >> 7, bb = o & 127;
            int sb = bb ^ ((r & 7) << 4);
            gload16((const char*)Xbf + ((size_t)(m0 + r) * ND + Ks * 64) * 2 + sb,
                    Ash[buf] + i * 8192 + w * 1024);
            gload16((const char*)W1B + ((size_t)(Ks * 512 + n0 + r) * 64) * 2 + sb,
                    Bsh[buf] + i * 8192 + w * 1024);
        }
    };

    f32x4 acc[2][4] = {};
    stage(0, 0);
    __syncthreads();
    for (int Ks = 0; Ks < 8; ++Ks) {
        int buf = Ks & 1;
        if (Ks < 7) stage(Ks + 1, buf ^ 1);
        #pragma unroll
        for (int k32 = 0; k32 < 2; ++k32) {
            int kb = (k32 * 32 + 8 * lk) * 2;
            bf16x8 a[2], bfr[4];
            #pragma unroll
            for (int mi = 0; mi < 2; ++mi) {
                int row = wm * 32 + mi * 16 + lr;
                a[mi] = *(const bf16x8*)(Ash[buf] + row * 128 + (kb ^ ((row & 7) << 4)));
            }
            #pragma unroll
            for (int ni = 0; ni < 4; ++ni) {
                int row = wn * 64 + ni * 16 + lr;
                bfr[ni] = *(const bf16x8*)(Bsh[buf] + row * 128 + (kb ^ ((row & 7) << 4)));
            }
            #pragma unroll
            for (int mi = 0; mi < 2; ++mi)
                #pragma unroll
                for (int ni = 0; ni < 4; ++ni)
                    acc[mi][ni] = __builtin_amdgcn_mfma_f32_16x16x32_bf16(a[mi], bfr[ni], acc[mi][ni], 0, 0, 0);
        }
        __syncthreads();
    }
    #pragma unroll
    for (int mi = 0; mi < 2; ++mi)
        #pragma unroll
        for (int ni = 0; ni < 4; ++ni) {
            int col = n0 + wn * 64 + ni * 16 + lr;
            float bb1 = b1[col];
            #pragma unroll
            for (int r = 0; r < 4; ++r) {
                int m = m0 + wm * 32 + mi * 16 + lk * 4 + r;
                hbf[(size_t)m * ND + col] = f2bf(acc[mi][ni][r] + bb1);
            }
        }
}

// ---------------- gating from X and WcT (f32, float4 loads) ----------------
__global__ __launch_bounds__(256) void gating_kernel(const float* __restrict__ X,
                                                     const float* __restrict__ WcT,
                                                     const float* __restrict__ probs,
                                                     int* __restrict__ idx1a, int* __restrict__ idx2a,
                                                     float* __restrict__ g1a, float* __restrict__ g2a,
                                                     int* __restrict__ pos1a, int* __restrict__ pos2a) {
    __shared__ float wc[NE * ND];           // 32KB
    const int tid = threadIdx.x;
    #pragma unroll
    for (int i = 0; i < 32; ++i) wc[tid + 256 * i] = WcT[tid + 256 * i];
    __syncthreads();
    const int w = tid >> 6, l = tid & 63;
    const float4* wc4 = (const float4*)wc;
    for (int j = 0; j < 8; ++j) {
        int tok = blockIdx.x * 32 + j * 4 + w;
        const float4* xrow = (const float4*)(X + (size_t)tok * ND);
        float4 x0 = xrow[l], x1 = xrow[l + 64];
        float acc[NE];
        #pragma unroll
        for (int e = 0; e < NE; ++e) {
            float4 w0 = wc4[e * 128 + l], w1 = wc4[e * 128 + l + 64];
            acc[e] = x0.x * w0.x + x0.y * w0.y + x0.z * w0.z + x0.w * w0.w
                   + x1.x * w1.x + x1.y * w1.y + x1.z * w1.z + x1.w * w1.w;
        }
        #pragma unroll
        for (int off = 32; off >= 1; off >>= 1)
            #pragma unroll
            for (int e = 0; e < NE; ++e) acc[e] += __shfl_xor(acc[e], off);

        if (l == 0) {
            float m = acc[0];
            #pragma unroll
            for (int e = 1; e < NE; ++e) m = fmaxf(m, acc[e]);
            float raw[NE]; float s = 0.f;
            #pragma unroll
            for (int e = 0; e < NE; ++e) { raw[e] = expf(acc[e] - m); s += raw[e]; }
            #pragma unroll
            for (int e = 0; e < NE; ++e) raw[e] = raw[e] / s;
            int i1 = 0; float g1 = raw[0];
            #pragma unroll
            for (int e = 1; e < NE; ++e) if (raw[e] > g1) { g1 = raw[e]; i1 = e; }
            int i2 = -1; float g2 = -1.f;
            #pragma unroll
            for (int e = 0; e < NE; ++e) if (e != i1 && raw[e] > g2) { g2 = raw[e]; i2 = e; }
            float denom = g1 + g2 + 1e-9f;
            float g1n = g1 / denom, g2n = g2 / denom;
            bool flag = probs[tok] < (g2n / 0.2f);
            idx1a[tok] = i1;
            idx2a[tok] = flag ? i2 : -1;
            g1a[tok] = g1n;
            g2a[tok] = g2n;
            pos1a[tok] = -1;
            pos2a[tok] = -1;
        }
    }
}

// ---------------- scan: one wave per (b,e), ballot prefix cumsum ----------------
__global__ __launch_bounds__(64) void scan_kernel(const int* __restrict__ idx1a,
                                                  const int* __restrict__ idx2a,
                                                  int* __restrict__ pos1a, int* __restrict__ pos2a,
                                                  int* __restrict__ slot_token) {
    const int bb = blockIdx.x;              // 64
    const int b = bb >> 4, e = bb & 15;
    const int l = threadIdx.x;
    int* slot = slot_token + (e * NB + b) * CAP;
    const unsigned long long below = (l == 0) ? 0ull : ((1ull << l) - 1ull);
    int c = 0;
    for (int base = 0; base < NN; base += 64) {
        int n = base + l;
        bool p = (idx1a[b * NN + n] == e);
        unsigned long long m = __ballot(p);
        int pre = __popcll(m & below);
        if (p) {
            int pos = c + pre;
            if (pos < CAP) { slot[pos] = n; pos1a[b * NN + n] = pos; }
        }
        c += __popcll(m);
    }
    int c2 = (c < CAP) ? c : CAP;
    for (int base = 0; base < NN; base += 64) {
        int n = base + l;
        bool p = (idx2a[b * NN + n] == e);
        unsigned long long m = __ballot(p);
        int pre = __popcll(m & below);
        if (p) {
            int pos = c2 + pre;
            if (pos < CAP) { slot[pos] = n; pos2a[b * NN + n] = pos; }
        }
        c2 += __popcll(m);
    }
    int nfill = (c2 < CAP) ? c2 : CAP;
    for (int i = nfill + l; i < CAP; i += 64) slot[i] = -1;
}

// ---------------- expert MFMA with expert->XCD swizzle ----------------
__global__ __launch_bounds__(512) void expert_mfma_kernel(const unsigned short* __restrict__ hbf,
                                                          const unsigned short* __restrict__ We1B,
                                                          const float* __restrict__ u,
                                                          const int* __restrict__ slot_token,
                                                          const float* __restrict__ zbuf,
                                                          float* __restrict__ s_slot) {
    __shared__ char Ash[65536];             // 64 slots x 512 k bf16, swizzled rows of 1024B
    __shared__ char Bsh[2][32768];          // 256 h x 64 k bf16, swizzled rows of 128B
    __shared__ float u_lds[NH];
    __shared__ float sbuf[8][32];
    __shared__ int toks[64];
    const int tid = threadIdx.x;
    const int w = tid >> 6, l = tid & 63;
    const int wm = w >> 2, wn = w & 3;      // 2 x 4 wave grid, wave tile 32x64
    const int lr = l & 15, lk = l >> 4;
    // XCD swizzle: all 16 blocks of an expert share an XCD (bid % 8 == e % 8)
    const int bid = blockIdx.x;
    const int e = (bid & 7) | ((bid >> 7) << 3);
    const int chunk = (bid >> 3) & 15;
    const int b = chunk >> 2, c0 = (chunk & 3) * 64;

    if (tid < 64) toks[tid] = slot_token[(e * NB + b) * CAP + c0 + tid];
    u_lds[tid] = u[e * NH + tid];
    u_lds[tid + 512] = u[e * NH + tid + 512];
    __syncthreads();
    // stage A: gather 64 token rows (full K) into LDS, swizzled source (rule #21)
    #pragma unroll
    for (int i = 0; i < 8; ++i) {
        int r = i * 8 + w;                  // wave-uniform row
        int t = toks[r];
        int sb = (l * 16) ^ ((r & 7) << 4);
        const char* src = (t >= 0) ? ((const char*)hbf + ((size_t)(b * NN + t) * ND) * 2 + sb)
                                   : ((const char*)zbuf + sb);
        gload16(src, Ash + i * 8192 + w * 1024);
    }
    auto stageB = [&](int s, int buf) {
        int Hc = s >> 3, Ks = s & 7;
        #pragma unroll
        for (int i = 0; i < 4; ++i) {
            int o = i * 8192 + tid * 16;
            int r = o >> 7, bb = o & 127;
            int sb = bb ^ ((r & 7) << 4);
            gload16((const char*)We1B + (((size_t)(e * 8 + Ks) * NH + Hc * 256 + r) * 64) * 2 + sb,
                    Bsh[buf] + i * 8192 + w * 1024);
        }
    };
    f32x4 acc[2][4] = {};
    float srow[2][4] = {};
    stageB(0, 0);
    __syncthreads();
    for (int s = 0; s < 32; ++s) {          // 4 H-chunks x 8 K-stages
        int buf = s & 1;
        if (s < 31) stageB(s + 1, buf ^ 1);
        #pragma unroll
        for (int k32 = 0; k32 < 2; ++k32) {
            int kbA = ((s & 7) * 64 + k32 * 32 + 8 * lk) * 2;
            int kbB = (k32 * 32 + 8 * lk) * 2;
            bf16x8 a[2], bfr[4];
            #pragma unroll
            for (int mi = 0; mi < 2; ++mi) {
                int row = wm * 32 + mi * 16 + lr;
                a[mi] = *(const bf16x8*)(Ash + row * 1024 + (kbA ^ ((row & 7) << 4)));
            }
            #pragma unroll
            for (int ni = 0; ni < 4; ++ni) {
                int row = wn * 64 + ni * 16 + lr;
                bfr[ni] = *(const bf16x8*)(Bsh[buf] + row * 128 + (kbB ^ ((row & 7) << 4)));
            }
            #pragma unroll
            for (int mi = 0; mi < 2; ++mi)
                #pragma unroll
                for (int ni = 0; ni < 4; ++ni)
                    acc[mi][ni] = __builtin_amdgcn_mfma_f32_16x16x32_bf16(a[mi], bfr[ni], acc[mi][ni], 0, 0, 0);
        }
        if ((s & 7) == 7) {                 // H-chunk done: fuse lrelu . u, reset acc
            int Hc = s >> 3;
            #pragma unroll
            for (int mi = 0; mi < 2; ++mi)
                #pragma unroll
                for (int ni = 0; ni < 4; ++ni) {
                    float uu = u_lds[Hc * 256 + wn * 64 + ni * 16 + lr];
                    #pragma unroll
                    for (int r = 0; r < 4; ++r) {
                        float x = acc[mi][ni][r];
                        x = (x > 0.f) ? x : 0.01f * x;
                        srow[mi][r] = fmaf(x, uu, srow[mi][r]);
                        acc[mi][ni][r] = 0.f;
                    }
                }
        }
        __syncthreads();
    }
    // reduce over the 16 col-lanes, then across the 4 N-waves via LDS
    #pragma unroll
    for (int off = 1; off < 16; off <<= 1)
        #pragma unroll
        for (int mi = 0; mi < 2; ++mi)
            #pragma unroll
            for (int r = 0; r < 4; ++r)
                srow[mi][r] += __shfl_xor(srow[mi][r], off);
    if (lr == 0) {
        #pragma unroll
        for (int mi = 0; mi < 2; ++mi)
            #pragma unroll
            for (int r = 0; r < 4; ++r)
                sbuf[w][mi * 16 + lk * 4 + r] = srow[mi][r];
    }
    __syncthreads();
    if (tid < 64) {
        int q = tid >> 5, rl = tid & 31;
        float s = sbuf[q * 4 + 0][rl] + sbuf[q * 4 + 1][rl] + sbuf[q * 4 + 2][rl] + sbuf[q * 4 + 3][rl];
        s_slot[(e * NB + b) * CAP + c0 + tid] = s;
    }
}

// ---------------- final combine + collapsed output projection ----------------
__global__ __launch_bounds__(256) void final_kernel(const int* __restrict__ idx1a, const int* __restrict__ idx2a,
                                                    const int* __restrict__ pos1a, const int* __restrict__ pos2a,
                                                    const float* __restrict__ g1a, const float* __restrict__ g2a,
                                                    const float* __restrict__ s_slot,
                                                    const float* __restrict__ b3, const float* __restrict__ W4,
                                                    const float* __restrict__ b4,
                                                    float* __restrict__ out) {
    int tok = blockIdx.x * 256 + threadIdx.x;
    int b = tok >> 11;
    float c0v = 0.f;
    #pragma unroll
    for (int j = 0; j < 4; ++j) c0v += b3[j] * W4[j];
    float s = c0v + b4[0];
    int p1 = pos1a[tok];
    if (p1 >= 0) s += g1a[tok] * s_slot[(idx1a[tok] * NB + b) * CAP + p1];
    int p2 = pos2a[tok];
    if (p2 >= 0) s += g2a[tok] * s_slot[(idx2a[tok] * NB + b) * CAP + p2];
    out[tok] = s;
}

extern "C" void kernel_launch(void* const* d_in, const int* in_sizes, int n_in,
                              void* d_out, int out_size, void* d_ws, size_t ws_size,
                              hipStream_t stream) {
    const float* X    = (const float*)d_in[0];
    const float* probs= (const float*)d_in[1];
    const float* W1   = (const float*)d_in[2];
    const float* b1   = (const float*)d_in[3];
    const float* Wg   = (const float*)d_in[4];
    const float* We1  = (const float*)d_in[5];
    const float* We2  = (const float*)d_in[6];
    const float* W3   = (const float*)d_in[7];
    const float* b3   = (const float*)d_in[8];
    const float* W4   = (const float*)d_in[9];
    const float* b4   = (const float*)d_in[10];
    float* out = (float*)d_out;

    char* ws = (char*)d_ws;
    size_t off = 0;
    auto alloc = [&](size_t bytes) { void* p = ws + off; off += (bytes + 255) & ~(size_t)255; return p; };
    unsigned short* Xbf  = (unsigned short*)alloc((size_t)NTOK * ND * 2);     // 8 MB
    unsigned short* hbf  = (unsigned short*)alloc((size_t)NTOK * ND * 2);     // 8 MB
    unsigned short* W1B  = (unsigned short*)alloc((size_t)ND * ND * 2);       // 512 KB
    unsigned short* We1B = (unsigned short*)alloc((size_t)NE * NH * ND * 2);  // 16 MB
    float* WcT     = (float*)alloc(NE * ND * 4);
    float* u       = (float*)alloc(NE * NH * 4);
    float* zbuf    = (float*)alloc(1024);
    int*   idx1a   = (int*)alloc(NTOK * 4);
    int*   idx2a   = (int*)alloc(NTOK * 4);
    int*   pos1a   = (int*)alloc(NTOK * 4);
    int*   pos2a   = (int*)alloc(NTOK * 4);
    float* g1a     = (float*)alloc(NTOK * 4);
    float* g2a     = (float*)alloc(NTOK * 4);
    int*   slot_tok= (int*)alloc(NE * NB * CAP * 4);
    float* s_slot  = (float*)alloc(NE * NB * CAP * 4);
    (void)ws_size; (void)in_sizes; (void)n_in; (void)out_size;

    prep_kernel<<<3136, 256, 0, stream>>>(X, W1, Wg, We1, We2, W3, W4,
                                          Xbf, W1B, We1B, WcT, u, zbuf);
    linear1_mfma_kernel<<<dim3(ND / 128, NTOK / 128), 512, 0, stream>>>(Xbf, W1B, b1, hbf);
    gating_kernel<<<NTOK / 32, 256, 0, stream>>>(X, WcT, probs, idx1a, idx2a, g1a, g2a, pos1a, pos2a);
    scan_kernel<<<NB * NE, 64, 0, stream>>>(idx1a, idx2a, pos1a, pos2a, slot_tok);
    expert_mfma_kernel<<<256, 512, 0, stream>>>(hbf, We1B, u, slot_tok, zbuf, s_slot);
    final_kernel<<<NTOK / 256, 256, 0, stream>>>(idx1a, idx2a, pos1a, pos2a, g1a, g2a, s_slot, b3, W4, b4, out);
}